// Round 12
// baseline (3051.028 us; speedup 1.0000x reference)
//
#include <hip/hip_runtime.h>

#define T_ 96
#define N_ 1140
#define F_ 64
#define H_ 32
#define E_ 22800
#define LH_ 250
#define G4_ 1000
#define OUT_ 2280
#define KIN_ 36480   // N_*H_
#define SPLITK 60
#define KC 32
#define BN 32

typedef _Float16 h2_t __attribute__((ext_vector_type(2)));

__device__ __forceinline__ float leaky02(float x){ return x > 0.f ? x : 0.2f*x; }
__device__ __forceinline__ float fsigm(float x){ return 1.f/(1.f + __expf(-x)); }
__device__ __forceinline__ float ftanh(float x){
  x = fminf(fmaxf(x, -15.f), 15.f);
  float t = __expf(2.f * x);
  return (t - 1.f) / (t + 1.f);
}
__device__ __forceinline__ unsigned packh2(float a, float b) {
  auto p = __builtin_amdgcn_cvt_pkrtz(a, b);   // __fp16 ext_vector(2)
  return __builtin_bit_cast(unsigned, p);
}
__device__ __forceinline__ float fdot2u(unsigned w, unsigned h, float acc) {
  return __builtin_amdgcn_fdot2(__builtin_bit_cast(h2_t, w),
                                __builtin_bit_cast(h2_t, h), acc, false);
}

// ---------------- GAT feature transform: H = x@W, HS = H@a_s, HD = H@a_d ----
__global__ void k_feat(const float* __restrict__ x, const float* __restrict__ W,
                       const float* __restrict__ as_, const float* __restrict__ ad_,
                       float* __restrict__ Hout, float* __restrict__ HS,
                       float* __restrict__ HD, int K) {
  int gid = blockIdx.x * blockDim.x + threadIdx.x;
  int row = gid >> 5; int c = gid & 31;
  if (row >= T_ * N_) return;
  const float* xr = x + (size_t)row * K;
  float acc = 0.f;
  for (int k = 0; k < K; ++k) acc += xr[k] * W[k * H_ + c];
  Hout[(size_t)row * H_ + c] = acc;
  float ps = acc * as_[c], pd = acc * ad_[c];
  #pragma unroll
  for (int off = 16; off > 0; off >>= 1) {
    ps += __shfl_xor(ps, off, 32);
    pd += __shfl_xor(pd, off, 32);
  }
  if (c == 0) { HS[row] = ps; HD[row] = pd; }
}

// ---------------- CSR build ------------------------------------------------
__global__ void k_count(const int* __restrict__ ei, int* __restrict__ counts) {
  int gid = blockIdx.x * blockDim.x + threadIdx.x;
  if (gid >= T_ * E_) return;
  int t = gid / E_; int k = gid - t * E_;
  int dst = ei[(size_t)t * 2 * E_ + E_ + k];
  atomicAdd(&counts[t * N_ + dst], 1);
}

__global__ void k_scan(const int* __restrict__ counts, int* __restrict__ offs,
                       int* __restrict__ cursor) {
  int t = blockIdx.x; int tid = threadIdx.x;
  int base = tid * 5;
  int v[5]; int s = 0;
  #pragma unroll
  for (int r = 0; r < 5; ++r) {
    int i = base + r;
    int c = (i < N_) ? counts[t * N_ + i] : 0;
    v[r] = c; s += c;
  }
  __shared__ int sh[256];
  sh[tid] = s; __syncthreads();
  for (int off = 1; off < 256; off <<= 1) {
    int add = (tid >= off) ? sh[tid - off] : 0;
    __syncthreads();
    sh[tid] += add;
    __syncthreads();
  }
  int run = sh[tid] - s;  // exclusive prefix of this thread's chunk
  #pragma unroll
  for (int r = 0; r < 5; ++r) {
    int i = base + r;
    if (i < N_) { offs[t * (N_ + 1) + i] = run; cursor[t * N_ + i] = run; }
    run += v[r];
  }
  if (tid == 255) offs[t * (N_ + 1) + N_] = sh[255];
}

__global__ void k_fill(const int* __restrict__ ei, int* __restrict__ cursor,
                       int* __restrict__ elist) {
  int gid = blockIdx.x * blockDim.x + threadIdx.x;
  if (gid >= T_ * E_) return;
  int t = gid / E_; int k = gid - t * E_;
  int src = ei[(size_t)t * 2 * E_ + k];
  int dst = ei[(size_t)t * 2 * E_ + E_ + k];
  int pos = atomicAdd(&cursor[t * N_ + dst], 1);
  elist[(size_t)t * E_ + pos] = src;
}

// ---------------- GAT attention aggregate (online softmax per dst) ---------
__global__ void k_aggr(const float* __restrict__ Hf, const float* __restrict__ HS,
                       const float* __restrict__ HD, const int* __restrict__ offs,
                       const int* __restrict__ elist, const float* __restrict__ b,
                       float* __restrict__ Xout, int relu) {
  int gid = blockIdx.x * blockDim.x + threadIdx.x;
  int row = gid >> 5; int c = gid & 31;
  if (row >= T_ * N_) return;
  int t = row / N_; int i = row - t * N_;
  float hd_i = HD[row];
  float m = leaky02(HS[row] + hd_i);   // self-loop
  float s = 1.f;
  float acc = Hf[(size_t)row * H_ + c];
  int e0 = offs[t * (N_ + 1) + i], e1 = offs[t * (N_ + 1) + i + 1];
  const int* el = elist + (size_t)t * E_;
  const float* Ht = Hf + (size_t)t * N_ * H_;
  const float* HSt = HS + t * N_;
  float hsA = 0.f, hvA = 0.f;
  if (e0 < e1) {
    int srcA = el[e0];
    hsA = HSt[srcA];
    hvA = Ht[(size_t)srcA * H_ + c];
  }
  for (int e = e0; e < e1; ++e) {
    float hs = hsA, hv = hvA;
    if (e + 1 < e1) {
      int srcA = el[e + 1];
      hsA = HSt[srcA];
      hvA = Ht[(size_t)srcA * H_ + c];
    }
    float eg = leaky02(hs + hd_i);
    float mn = fmaxf(m, eg);
    float scl = __expf(m - mn);
    float p = __expf(eg - mn);
    s = s * scl + p;
    acc = acc * scl + p * hv;
    m = mn;
  }
  float val = acc / s + b[c];
  if (relu) val = fmaxf(val, 0.f);
  Xout[(size_t)row * H_ + c] = val;
}

// ------- LSTM0 input GEMM (f16 dot2): (96 x 36480) @ (36480 x 1000)^T ------
__global__ void k_gemm(const float* __restrict__ X, const float* __restrict__ Wih,
                       float* __restrict__ Gpart) {
  __shared__ unsigned Xs[T_][KC / 2 + 1];   // f16 pairs along K
  __shared__ unsigned Ws[BN][KC / 2 + 1];
  int j0 = blockIdx.x * BN;
  int sp = blockIdx.y;
  int tid = threadIdx.x;
  int jj = tid & 7;    // 8 j-groups of 4
  int tt = tid >> 3;   // 16 t-groups of 6
  float acc[6][4] = {};
  int kbeg = sp * (KIN_ / SPLITK);
  int kend = kbeg + (KIN_ / SPLITK);
  for (int k0 = kbeg; k0 < kend; k0 += KC) {
    for (int idx = tid; idx < T_ * (KC / 2); idx += 128) {
      int tr = idx >> 4; int kk = idx & 15;
      const float2 v = *(const float2*)(X + (size_t)tr * KIN_ + k0 + 2 * kk);
      Xs[tr][kk] = packh2(v.x, v.y);
    }
    for (int idx = tid; idx < BN * (KC / 2); idx += 128) {
      int jr = idx >> 4; int kk = idx & 15;
      int j = j0 + jr;
      unsigned v = 0;
      if (j < G4_) {
        const float2 w = *(const float2*)(Wih + (size_t)j * KIN_ + k0 + 2 * kk);
        v = packh2(w.x, w.y);
      }
      Ws[jr][kk] = v;
    }
    __syncthreads();
    for (int kk = 0; kk < KC / 2; ++kk) {
      unsigned xv[6], wv[4];
      #pragma unroll
      for (int r = 0; r < 6; ++r) xv[r] = Xs[tt * 6 + r][kk];
      #pragma unroll
      for (int q = 0; q < 4; ++q) wv[q] = Ws[jj * 4 + q][kk];
      #pragma unroll
      for (int r = 0; r < 6; ++r)
        #pragma unroll
        for (int q = 0; q < 4; ++q)
          acc[r][q] = fdot2u(wv[q], xv[r], acc[r][q]);
    }
    __syncthreads();
  }
  #pragma unroll
  for (int r = 0; r < 6; ++r) {
    int t = tt * 6 + r;
    #pragma unroll
    for (int q = 0; q < 4; ++q) {
      int j = j0 + jj * 4 + q;
      if (j < G4_) Gpart[((size_t)sp * T_ + t) * 1024 + j] = acc[r][q];
    }
  }
}

// G0 reduced with gate-interleaved layout: G0[t*1000 + j*4 + g]
__global__ void k_gred(const float* __restrict__ Gpart, const float* __restrict__ bih,
                       const float* __restrict__ bhh, float* __restrict__ G0) {
  int idx = blockIdx.x * blockDim.x + threadIdx.x;
  if (idx >= T_ * G4_) return;
  int t = idx / G4_; int jg = idx - t * G4_;
  int j = jg >> 2, g = jg & 3;
  int c = g * LH_ + j;                      // gate-major column in Gpart
  float s = bih[c] + bhh[c];
  for (int sp = 0; sp < SPLITK; ++sp) s += Gpart[((size_t)sp * T_ + t) * 1024 + c];
  G0[idx] = s;
}

// ---------------- single-WG LSTM layer recurrence (3-way K-split) ----------
// ONE workgroup, 768 threads (12 waves, 3/SIMD -> 170-VGPR budget). Wave w,
// lane l<63: unit u = w*21 + l/3, K-third r = l%3 (42 f16-pairs each).
// Gates i,f,g in VGPRs (126 u32 -- fits; R11's 192 spilled to scratch:
// VGPR_Count=128 + WRITE_SIZE=444KB were the tell). o-gate rows in LDS
// [mm*768+tid] (2-way = free). h as _Float16[256] LDS double buffer
// (ds_write_b16 per unit; uint2 broadcast reads at 42-u32 offsets ->
// distinct banks). 3-lane reduce via dynamic-lane shfl. 1 barrier/step,
// zero atomics; layer ordering carried by kernel ordering.
__global__ void __launch_bounds__(768, 3) k_lstm_seq(
    const float* __restrict__ Wrec,   // [4*250][250] rows g*250+u, fp32
    const float* __restrict__ GP,     // [96][1000] gate-interleaved u*4+g
    const float* __restrict__ hinit,  // [250]
    const float* __restrict__ cinit,  // [250]
    float* __restrict__ hseq_out,     // role0: [96][256]
    float* __restrict__ ylast,        // role1: [250]
    int role) {
  __shared__ __align__(8) _Float16 ldsH[2][256];
  __shared__ unsigned ldsWO[42 * 768];   // 129 KiB
  int tid = threadIdx.x;
  int w = tid >> 6, l = tid & 63;
  int u = w * 21 + l / 3;
  int r = l % 3;
  bool act = (l < 63) && (u < LH_);
  int bl = l - r;                        // base lane of this unit's triple

  // ---- weight preload: local idx 0..41 -> global pair m = r*42+idx ----
  unsigned wI[42], wF[42], wG[42];
  {
    int uc = act ? u : 0;
    const float* rI = Wrec + (size_t)(0 * LH_ + uc) * LH_;
    const float* rF = Wrec + (size_t)(1 * LH_ + uc) * LH_;
    const float* rG = Wrec + (size_t)(2 * LH_ + uc) * LH_;
    const float* rO = Wrec + (size_t)(3 * LH_ + uc) * LH_;
    #pragma unroll 2
    for (int idx = 0; idx < 42; ++idx) {
      int m = r * 42 + idx;
      bool ok = act && (m < 125);
      int k = 2 * m;
      float2 vI = ok ? *(const float2*)(rI + k) : make_float2(0.f, 0.f);
      float2 vF = ok ? *(const float2*)(rF + k) : make_float2(0.f, 0.f);
      float2 vG = ok ? *(const float2*)(rG + k) : make_float2(0.f, 0.f);
      float2 vO = ok ? *(const float2*)(rO + k) : make_float2(0.f, 0.f);
      wI[idx] = packh2(vI.x, vI.y);
      wF[idx] = packh2(vF.x, vF.y);
      wG[idx] = packh2(vG.x, vG.y);
      ldsWO[idx * 768 + tid] = packh2(vO.x, vO.y);
    }
  }
  // ---- init h buffers (tail [250..255] stays zero; weights there are 0) ----
  if (tid < 256) {
    ldsH[0][tid] = (tid < LH_) ? (_Float16)hinit[tid] : (_Float16)0.f;
    ldsH[1][tid] = (_Float16)0.f;
  }
  float c = act ? cinit[u] : 0.f;
  __syncthreads();

  for (int p = 0; p < T_; ++p) {
    int rb = p & 1, wb = rb ^ 1;
    float4 gp = make_float4(0.f, 0.f, 0.f, 0.f);
    if (act) gp = *(const float4*)(GP + (size_t)p * G4_ + 4 * u);
    float sI = 0.f, sF = 0.f, sG = 0.f, sO = 0.f;
    const uint2* h2p = (const uint2*)&ldsH[rb][0];   // u64-aligned pairs-of-pairs
    #pragma unroll 7
    for (int q = 0; q < 21; ++q) {
      uint2 hv = h2p[r * 21 + q];
      int i0 = 2 * q;
      sI = fdot2u(wI[i0], hv.x, sI);
      sF = fdot2u(wF[i0], hv.x, sF);
      sG = fdot2u(wG[i0], hv.x, sG);
      sO = fdot2u(ldsWO[i0 * 768 + tid], hv.x, sO);
      sI = fdot2u(wI[i0 + 1], hv.y, sI);
      sF = fdot2u(wF[i0 + 1], hv.y, sF);
      sG = fdot2u(wG[i0 + 1], hv.y, sG);
      sO = fdot2u(ldsWO[(i0 + 1) * 768 + tid], hv.y, sO);
    }
    // reduce across the unit's 3 lanes (bl, bl+1, bl+2)
    float tI = __shfl(sI, bl) + __shfl(sI, bl + 1) + __shfl(sI, bl + 2);
    float tF = __shfl(sF, bl) + __shfl(sF, bl + 1) + __shfl(sF, bl + 2);
    float tG = __shfl(sG, bl) + __shfl(sG, bl + 1) + __shfl(sG, bl + 2);
    float tO = __shfl(sO, bl) + __shfl(sO, bl + 1) + __shfl(sO, bl + 2);
    float preI = tI + gp.x, preF = tF + gp.y;
    float preG = tG + gp.z, preO = tO + gp.w;
    c = fsigm(preF) * c + fsigm(preI) * ftanh(preG);
    float h = act ? (fsigm(preO) * ftanh(c)) : 0.f;
    if (act && r == 0) {
      ldsH[wb][u] = (_Float16)h;
      if (role == 0) hseq_out[p * 256 + u] = h;
      if (role == 1 && p == T_ - 1) ylast[u] = h;
    }
    __syncthreads();
  }
}

// ------- batch layer-1 input projection: P[t] = Wih1 @ h0[t] + b -----------
// grid 96*4 WGs x 256: WG (t, b) computes outputs o = b*256+tid (o = j*4+g).
__global__ void k_pgemm(const float* __restrict__ h0seq, const float* __restrict__ Wih1,
                        const float* __restrict__ bih1, const float* __restrict__ bhh1,
                        float* __restrict__ P) {
  __shared__ float hs[256];
  int t = blockIdx.x >> 2, b = blockIdx.x & 3;
  int tid = threadIdx.x;
  hs[tid] = (tid < LH_) ? h0seq[t * 256 + tid] : 0.f;
  __syncthreads();
  int o = b * 256 + tid;
  if (o >= G4_) return;
  int j = o >> 2, g = o & 3;
  const float* wr = Wih1 + (size_t)(g * LH_ + j) * LH_;
  float s = bih1[g * LH_ + j] + bhh1[g * LH_ + j];
  #pragma unroll 2
  for (int k = 0; k < LH_; k += 2) {
    float2 w2 = *(const float2*)(wr + k);
    s += w2.x * hs[k] + w2.y * hs[k + 1];
  }
  P[(size_t)t * G4_ + o] = s;
}

// ---------------- 4 FC heads ----------------------------------------------
__global__ void k_fc(const float* __restrict__ ylast,
                     const float* __restrict__ Wa, const float* __restrict__ ba,
                     const float* __restrict__ Wb, const float* __restrict__ bb,
                     const float* __restrict__ Wc, const float* __restrict__ bc,
                     const float* __restrict__ Wd, const float* __restrict__ bd,
                     float* __restrict__ out) {
  int wg = blockIdx.x * 4 + (threadIdx.x >> 6);
  int lane = threadIdx.x & 63;
  if (wg >= 4 * OUT_) return;
  int head = wg / OUT_, o = wg - head * OUT_;
  const float* W = head == 0 ? Wa : head == 1 ? Wb : head == 2 ? Wc : Wd;
  const float* b = head == 0 ? ba : head == 1 ? bb : head == 2 ? bc : bd;
  float s = 0.f;
  #pragma unroll
  for (int r = 0; r < 4; ++r) {
    int idx = r * 64 + lane;
    if (idx < LH_) s += ylast[idx] * W[(size_t)o * LH_ + idx];
  }
  #pragma unroll
  for (int off = 32; off > 0; off >>= 1) s += __shfl_xor(s, off, 64);
  if (lane == 0) out[wg] = s + b[o];
}

// ---------------- launch ---------------------------------------------------
extern "C" void kernel_launch(void* const* d_in, const int* in_sizes, int n_in,
                              void* d_out, int out_size, void* d_ws, size_t ws_size,
                              hipStream_t stream) {
  const float* nodes = (const float*)d_in[0];
  const int*   ei    = (const int*)d_in[1];
  const float* W1    = (const float*)d_in[3];
  const float* as1   = (const float*)d_in[4];
  const float* ad1   = (const float*)d_in[5];
  const float* b1    = (const float*)d_in[6];
  const float* W2    = (const float*)d_in[7];
  const float* as2   = (const float*)d_in[8];
  const float* ad2   = (const float*)d_in[9];
  const float* b2    = (const float*)d_in[10];
  const float* Wih0  = (const float*)d_in[11];
  const float* Whh0  = (const float*)d_in[12];
  const float* bih0  = (const float*)d_in[13];
  const float* bhh0  = (const float*)d_in[14];
  const float* Wih1  = (const float*)d_in[15];
  const float* Whh1  = (const float*)d_in[16];
  const float* bih1  = (const float*)d_in[17];
  const float* bhh1  = (const float*)d_in[18];
  const float* h0    = (const float*)d_in[19];
  const float* c0    = (const float*)d_in[20];
  const float* fW1   = (const float*)d_in[21];
  const float* fb1   = (const float*)d_in[22];
  const float* fW2   = (const float*)d_in[23];
  const float* fb2   = (const float*)d_in[24];
  const float* fW3   = (const float*)d_in[25];
  const float* fb3   = (const float*)d_in[26];
  const float* fW4   = (const float*)d_in[27];
  const float* fb4   = (const float*)d_in[28];
  float* out = (float*)d_out;

  // workspace layout (bytes). Gpart overlaps dead Hbuf/HS/HD/X1 region.
  const size_t o_Gpart  = 0;          // 60*96*1024*4 = 23,592,960
  const size_t o_H      = 0;
  const size_t o_HS     = 14008320;
  const size_t o_HD     = 14446080;
  const size_t o_X1     = 14883840;
  const size_t o_X2     = 28892160;
  const size_t o_counts = 42900480;
  const size_t o_offs   = 43338240;
  const size_t o_cursor = 43776512;
  const size_t o_elist  = 44214272;
  const size_t o_G0     = 52969472;   // 384,000
  const size_t o_ylast  = 53353472;   // 1,024
  const size_t o_h0seq  = 53354496;   // 96*256*4 = 98,304
  const size_t o_P      = 53452800;   // 96*1000*4 = 384,000
  const size_t total    = 53836800;
  if (ws_size < total) return;  // leaves d_out poisoned -> visible failure

  char* ws = (char*)d_ws;
  float* Gpart  = (float*)(ws + o_Gpart);
  float* Hbuf   = (float*)(ws + o_H);
  float* HS     = (float*)(ws + o_HS);
  float* HD     = (float*)(ws + o_HD);
  float* X1     = (float*)(ws + o_X1);
  float* X2     = (float*)(ws + o_X2);
  int*   counts = (int*)(ws + o_counts);
  int*   offs   = (int*)(ws + o_offs);
  int*   cursor = (int*)(ws + o_cursor);
  int*   elist  = (int*)(ws + o_elist);
  float* G0     = (float*)(ws + o_G0);
  float* ylast  = (float*)(ws + o_ylast);
  float* h0seq  = (float*)(ws + o_h0seq);
  float* P      = (float*)(ws + o_P);

  (void)hipMemsetAsync(counts, 0, (size_t)T_ * N_ * 4, stream);

  const int rows_grid = (T_ * N_ * H_) / 256;   // 13680
  const int eg = (T_ * E_ + 255) / 256;         // 8550

  // GAT layer 1
  k_feat<<<rows_grid, 256, 0, stream>>>(nodes, W1, as1, ad1, Hbuf, HS, HD, F_);
  k_count<<<eg, 256, 0, stream>>>(ei, counts);
  k_scan<<<T_, 256, 0, stream>>>(counts, offs, cursor);
  k_fill<<<eg, 256, 0, stream>>>(ei, cursor, elist);
  k_aggr<<<rows_grid, 256, 0, stream>>>(Hbuf, HS, HD, offs, elist, b1, X1, 1);
  // GAT layer 2
  k_feat<<<rows_grid, 256, 0, stream>>>(X1, W2, as2, ad2, Hbuf, HS, HD, H_);
  k_aggr<<<rows_grid, 256, 0, stream>>>(Hbuf, HS, HD, offs, elist, b2, X2, 0);
  // LSTM0 input projection (f16 dot2, SPLITK=60)
  k_gemm<<<dim3(32, SPLITK), 128, 0, stream>>>(X2, Wih0, Gpart);
  k_gred<<<(T_ * G4_ + 255) / 256, 256, 0, stream>>>(Gpart, bih0, bhh0, G0);
  // layer-0 recurrence (single WG, register-resident weights)
  k_lstm_seq<<<1, 768, 0, stream>>>(Whh0, G0, h0, c0, h0seq, ylast, 0);
  // batch layer-1 input projection over all t
  k_pgemm<<<T_ * 4, 256, 0, stream>>>(h0seq, Wih1, bih1, bhh1, P);
  // layer-1 recurrence (single WG)
  k_lstm_seq<<<1, 768, 0, stream>>>(Whh1, P, h0 + LH_, c0 + LH_, h0seq, ylast, 1);
  // FC heads
  k_fc<<<OUT_, 256, 0, stream>>>(ylast, fW1, fb1, fW2, fb2, fW3, fb3, fW4, fb4, out);
}

// Round 13
// 1357.403 us; speedup vs baseline: 2.2477x; 2.2477x over previous
//
#include <hip/hip_runtime.h>

#define T_ 96
#define N_ 1140
#define F_ 64
#define H_ 32
#define E_ 22800
#define LH_ 250
#define G4_ 1000
#define OUT_ 2280
#define KIN_ 36480   // N_*H_
#define SPLITK 60
#define KC 32
#define BN 32

typedef _Float16 h2_t __attribute__((ext_vector_type(2)));

__device__ __forceinline__ float leaky02(float x){ return x > 0.f ? x : 0.2f*x; }
__device__ __forceinline__ float fsigm(float x){ return 1.f/(1.f + __expf(-x)); }
__device__ __forceinline__ float ftanh(float x){
  x = fminf(fmaxf(x, -15.f), 15.f);
  float t = __expf(2.f * x);
  return (t - 1.f) / (t + 1.f);
}
__device__ __forceinline__ unsigned packh2(float a, float b) {
  auto p = __builtin_amdgcn_cvt_pkrtz(a, b);   // __fp16 ext_vector(2)
  return __builtin_bit_cast(unsigned, p);
}
__device__ __forceinline__ float fdot2u(unsigned w, unsigned h, float acc) {
  return __builtin_amdgcn_fdot2(__builtin_bit_cast(h2_t, w),
                                __builtin_bit_cast(h2_t, h), acc, false);
}

// ---------------- GAT feature transform: H = x@W, HS = H@a_s, HD = H@a_d ----
__global__ void k_feat(const float* __restrict__ x, const float* __restrict__ W,
                       const float* __restrict__ as_, const float* __restrict__ ad_,
                       float* __restrict__ Hout, float* __restrict__ HS,
                       float* __restrict__ HD, int K) {
  int gid = blockIdx.x * blockDim.x + threadIdx.x;
  int row = gid >> 5; int c = gid & 31;
  if (row >= T_ * N_) return;
  const float* xr = x + (size_t)row * K;
  float acc = 0.f;
  for (int k = 0; k < K; ++k) acc += xr[k] * W[k * H_ + c];
  Hout[(size_t)row * H_ + c] = acc;
  float ps = acc * as_[c], pd = acc * ad_[c];
  #pragma unroll
  for (int off = 16; off > 0; off >>= 1) {
    ps += __shfl_xor(ps, off, 32);
    pd += __shfl_xor(pd, off, 32);
  }
  if (c == 0) { HS[row] = ps; HD[row] = pd; }
}

// ---------------- CSR build ------------------------------------------------
__global__ void k_count(const int* __restrict__ ei, int* __restrict__ counts) {
  int gid = blockIdx.x * blockDim.x + threadIdx.x;
  if (gid >= T_ * E_) return;
  int t = gid / E_; int k = gid - t * E_;
  int dst = ei[(size_t)t * 2 * E_ + E_ + k];
  atomicAdd(&counts[t * N_ + dst], 1);
}

__global__ void k_scan(const int* __restrict__ counts, int* __restrict__ offs,
                       int* __restrict__ cursor) {
  int t = blockIdx.x; int tid = threadIdx.x;
  int base = tid * 5;
  int v[5]; int s = 0;
  #pragma unroll
  for (int r = 0; r < 5; ++r) {
    int i = base + r;
    int c = (i < N_) ? counts[t * N_ + i] : 0;
    v[r] = c; s += c;
  }
  __shared__ int sh[256];
  sh[tid] = s; __syncthreads();
  for (int off = 1; off < 256; off <<= 1) {
    int add = (tid >= off) ? sh[tid - off] : 0;
    __syncthreads();
    sh[tid] += add;
    __syncthreads();
  }
  int run = sh[tid] - s;  // exclusive prefix of this thread's chunk
  #pragma unroll
  for (int r = 0; r < 5; ++r) {
    int i = base + r;
    if (i < N_) { offs[t * (N_ + 1) + i] = run; cursor[t * N_ + i] = run; }
    run += v[r];
  }
  if (tid == 255) offs[t * (N_ + 1) + N_] = sh[255];
}

__global__ void k_fill(const int* __restrict__ ei, int* __restrict__ cursor,
                       int* __restrict__ elist) {
  int gid = blockIdx.x * blockDim.x + threadIdx.x;
  if (gid >= T_ * E_) return;
  int t = gid / E_; int k = gid - t * E_;
  int src = ei[(size_t)t * 2 * E_ + k];
  int dst = ei[(size_t)t * 2 * E_ + E_ + k];
  int pos = atomicAdd(&cursor[t * N_ + dst], 1);
  elist[(size_t)t * E_ + pos] = src;
}

// ---------------- GAT attention aggregate (online softmax per dst) ---------
__global__ void k_aggr(const float* __restrict__ Hf, const float* __restrict__ HS,
                       const float* __restrict__ HD, const int* __restrict__ offs,
                       const int* __restrict__ elist, const float* __restrict__ b,
                       float* __restrict__ Xout, int relu) {
  int gid = blockIdx.x * blockDim.x + threadIdx.x;
  int row = gid >> 5; int c = gid & 31;
  if (row >= T_ * N_) return;
  int t = row / N_; int i = row - t * N_;
  float hd_i = HD[row];
  float m = leaky02(HS[row] + hd_i);   // self-loop
  float s = 1.f;
  float acc = Hf[(size_t)row * H_ + c];
  int e0 = offs[t * (N_ + 1) + i], e1 = offs[t * (N_ + 1) + i + 1];
  const int* el = elist + (size_t)t * E_;
  const float* Ht = Hf + (size_t)t * N_ * H_;
  const float* HSt = HS + t * N_;
  float hsA = 0.f, hvA = 0.f;
  if (e0 < e1) {
    int srcA = el[e0];
    hsA = HSt[srcA];
    hvA = Ht[(size_t)srcA * H_ + c];
  }
  for (int e = e0; e < e1; ++e) {
    float hs = hsA, hv = hvA;
    if (e + 1 < e1) {
      int srcA = el[e + 1];
      hsA = HSt[srcA];
      hvA = Ht[(size_t)srcA * H_ + c];
    }
    float eg = leaky02(hs + hd_i);
    float mn = fmaxf(m, eg);
    float scl = __expf(m - mn);
    float p = __expf(eg - mn);
    s = s * scl + p;
    acc = acc * scl + p * hv;
    m = mn;
  }
  float val = acc / s + b[c];
  if (relu) val = fmaxf(val, 0.f);
  Xout[(size_t)row * H_ + c] = val;
}

// ------- LSTM0 input GEMM (f16 dot2): (96 x 36480) @ (36480 x 1000)^T ------
__global__ void k_gemm(const float* __restrict__ X, const float* __restrict__ Wih,
                       float* __restrict__ Gpart) {
  __shared__ unsigned Xs[T_][KC / 2 + 1];   // f16 pairs along K
  __shared__ unsigned Ws[BN][KC / 2 + 1];
  int j0 = blockIdx.x * BN;
  int sp = blockIdx.y;
  int tid = threadIdx.x;
  int jj = tid & 7;    // 8 j-groups of 4
  int tt = tid >> 3;   // 16 t-groups of 6
  float acc[6][4] = {};
  int kbeg = sp * (KIN_ / SPLITK);
  int kend = kbeg + (KIN_ / SPLITK);
  for (int k0 = kbeg; k0 < kend; k0 += KC) {
    for (int idx = tid; idx < T_ * (KC / 2); idx += 128) {
      int tr = idx >> 4; int kk = idx & 15;
      const float2 v = *(const float2*)(X + (size_t)tr * KIN_ + k0 + 2 * kk);
      Xs[tr][kk] = packh2(v.x, v.y);
    }
    for (int idx = tid; idx < BN * (KC / 2); idx += 128) {
      int jr = idx >> 4; int kk = idx & 15;
      int j = j0 + jr;
      unsigned v = 0;
      if (j < G4_) {
        const float2 w = *(const float2*)(Wih + (size_t)j * KIN_ + k0 + 2 * kk);
        v = packh2(w.x, w.y);
      }
      Ws[jr][kk] = v;
    }
    __syncthreads();
    for (int kk = 0; kk < KC / 2; ++kk) {
      unsigned xv[6], wv[4];
      #pragma unroll
      for (int r = 0; r < 6; ++r) xv[r] = Xs[tt * 6 + r][kk];
      #pragma unroll
      for (int q = 0; q < 4; ++q) wv[q] = Ws[jj * 4 + q][kk];
      #pragma unroll
      for (int r = 0; r < 6; ++r)
        #pragma unroll
        for (int q = 0; q < 4; ++q)
          acc[r][q] = fdot2u(wv[q], xv[r], acc[r][q]);
    }
    __syncthreads();
  }
  #pragma unroll
  for (int r = 0; r < 6; ++r) {
    int t = tt * 6 + r;
    #pragma unroll
    for (int q = 0; q < 4; ++q) {
      int j = j0 + jj * 4 + q;
      if (j < G4_) Gpart[((size_t)sp * T_ + t) * 1024 + j] = acc[r][q];
    }
  }
}

// G0 reduced with gate-interleaved layout: G0[t*1000 + j*4 + g]
__global__ void k_gred(const float* __restrict__ Gpart, const float* __restrict__ bih,
                       const float* __restrict__ bhh, float* __restrict__ G0) {
  int idx = blockIdx.x * blockDim.x + threadIdx.x;
  if (idx >= T_ * G4_) return;
  int t = idx / G4_; int jg = idx - t * G4_;
  int j = jg >> 2, g = jg & 3;
  int c = g * LH_ + j;                      // gate-major column in Gpart
  float s = bih[c] + bhh[c];
  for (int sp = 0; sp < SPLITK; ++sp) s += Gpart[((size_t)sp * T_ + t) * 1024 + c];
  G0[idx] = s;
}

// ---------------- single-WG LSTM layer recurrence (3-way K-split) ----------
// ONE workgroup, 768 threads (12 waves, 3/SIMD -> 170-VGPR cap per m69).
// Wave w, lane l<63: unit u = w*21 + l/3, K-third r = l%3 (42 f16-pairs).
// Gates i,f,g in VGPRs (126 u32); o-gate in LDS as uint2 [q*768+tid]
// (2 lanes/bank = free). ALL loops FULLY unrolled: R12's partial unroll
// made wI[] runtime-indexed -> local memory (VGPR_Count=68, 3x slower;
// rule #20). h as _Float16[256] LDS double buffer; 1 barrier/step; zero
// atomics; layer ordering carried by kernel ordering.
__global__ void __launch_bounds__(768, 3) k_lstm_seq(
    const float* __restrict__ Wrec,   // [4*250][250] rows g*250+u, fp32
    const float* __restrict__ GP,     // [96][1000] gate-interleaved u*4+g
    const float* __restrict__ hinit,  // [250]
    const float* __restrict__ cinit,  // [250]
    float* __restrict__ hseq_out,     // role0: [96][256]
    float* __restrict__ ylast,        // role1: [250]
    int role) {
  __shared__ __align__(8) _Float16 ldsH[2][256];
  __shared__ uint2 ldsWO[21 * 768];   // 129 KiB
  int tid = threadIdx.x;
  int w = tid >> 6, l = tid & 63;
  int u = w * 21 + l / 3;
  int r = l % 3;
  bool act = (l < 63) && (u < LH_);
  int bl = l - r;                        // base lane of this unit's triple

  // ---- weight preload (FULLY unrolled; static indices only) ----
  unsigned wI[42], wF[42], wG[42];
  {
    int uc = act ? u : 0;
    const float* rI = Wrec + (size_t)(0 * LH_ + uc) * LH_;
    const float* rF = Wrec + (size_t)(1 * LH_ + uc) * LH_;
    const float* rG = Wrec + (size_t)(2 * LH_ + uc) * LH_;
    const float* rO = Wrec + (size_t)(3 * LH_ + uc) * LH_;
    #pragma unroll
    for (int q = 0; q < 21; ++q) {
      int m0 = r * 42 + 2 * q, m1 = m0 + 1;
      bool ok0 = act && (m0 < 125), ok1 = act && (m1 < 125);
      float2 vI0 = ok0 ? *(const float2*)(rI + 2 * m0) : make_float2(0.f, 0.f);
      float2 vF0 = ok0 ? *(const float2*)(rF + 2 * m0) : make_float2(0.f, 0.f);
      float2 vG0 = ok0 ? *(const float2*)(rG + 2 * m0) : make_float2(0.f, 0.f);
      float2 vO0 = ok0 ? *(const float2*)(rO + 2 * m0) : make_float2(0.f, 0.f);
      float2 vI1 = ok1 ? *(const float2*)(rI + 2 * m1) : make_float2(0.f, 0.f);
      float2 vF1 = ok1 ? *(const float2*)(rF + 2 * m1) : make_float2(0.f, 0.f);
      float2 vG1 = ok1 ? *(const float2*)(rG + 2 * m1) : make_float2(0.f, 0.f);
      float2 vO1 = ok1 ? *(const float2*)(rO + 2 * m1) : make_float2(0.f, 0.f);
      wI[2 * q]     = packh2(vI0.x, vI0.y);
      wI[2 * q + 1] = packh2(vI1.x, vI1.y);
      wF[2 * q]     = packh2(vF0.x, vF0.y);
      wF[2 * q + 1] = packh2(vF1.x, vF1.y);
      wG[2 * q]     = packh2(vG0.x, vG0.y);
      wG[2 * q + 1] = packh2(vG1.x, vG1.y);
      ldsWO[q * 768 + tid] = make_uint2(packh2(vO0.x, vO0.y), packh2(vO1.x, vO1.y));
    }
  }
  // ---- init h buffers (tail [250..255] stays zero; weights there are 0) ----
  if (tid < 256) {
    ldsH[0][tid] = (tid < LH_) ? (_Float16)hinit[tid] : (_Float16)0.f;
    ldsH[1][tid] = (_Float16)0.f;
  }
  float c = act ? cinit[u] : 0.f;
  __syncthreads();

  for (int p = 0; p < T_; ++p) {
    int rb = p & 1, wb = rb ^ 1;
    float4 gp = make_float4(0.f, 0.f, 0.f, 0.f);
    if (act) gp = *(const float4*)(GP + (size_t)p * G4_ + 4 * u);
    float sI = 0.f, sF = 0.f, sG = 0.f, sO = 0.f;
    const uint2* h2p = (const uint2*)&ldsH[rb][0];   // pair-of-f16pairs
    #pragma unroll
    for (int q = 0; q < 21; ++q) {
      uint2 hv = h2p[r * 21 + q];
      uint2 wo = ldsWO[q * 768 + tid];
      sI = fdot2u(wI[2 * q], hv.x, sI);
      sF = fdot2u(wF[2 * q], hv.x, sF);
      sG = fdot2u(wG[2 * q], hv.x, sG);
      sO = fdot2u(wo.x, hv.x, sO);
      sI = fdot2u(wI[2 * q + 1], hv.y, sI);
      sF = fdot2u(wF[2 * q + 1], hv.y, sF);
      sG = fdot2u(wG[2 * q + 1], hv.y, sG);
      sO = fdot2u(wo.y, hv.y, sO);
    }
    // reduce across the unit's 3 lanes (bl, bl+1, bl+2)
    float tI = __shfl(sI, bl) + __shfl(sI, bl + 1) + __shfl(sI, bl + 2);
    float tF = __shfl(sF, bl) + __shfl(sF, bl + 1) + __shfl(sF, bl + 2);
    float tG = __shfl(sG, bl) + __shfl(sG, bl + 1) + __shfl(sG, bl + 2);
    float tO = __shfl(sO, bl) + __shfl(sO, bl + 1) + __shfl(sO, bl + 2);
    float preI = tI + gp.x, preF = tF + gp.y;
    float preG = tG + gp.z, preO = tO + gp.w;
    c = fsigm(preF) * c + fsigm(preI) * ftanh(preG);
    float h = act ? (fsigm(preO) * ftanh(c)) : 0.f;
    if (act && r == 0) {
      ldsH[wb][u] = (_Float16)h;
      if (role == 0) hseq_out[p * 256 + u] = h;
      if (role == 1 && p == T_ - 1) ylast[u] = h;
    }
    __syncthreads();
  }
}

// ------- batch layer-1 input projection: P[t] = Wih1 @ h0[t] + b -----------
// grid 96*4 WGs x 256: WG (t, b) computes outputs o = b*256+tid (o = j*4+g).
__global__ void k_pgemm(const float* __restrict__ h0seq, const float* __restrict__ Wih1,
                        const float* __restrict__ bih1, const float* __restrict__ bhh1,
                        float* __restrict__ P) {
  __shared__ float hs[256];
  int t = blockIdx.x >> 2, b = blockIdx.x & 3;
  int tid = threadIdx.x;
  hs[tid] = (tid < LH_) ? h0seq[t * 256 + tid] : 0.f;
  __syncthreads();
  int o = b * 256 + tid;
  if (o >= G4_) return;
  int j = o >> 2, g = o & 3;
  const float* wr = Wih1 + (size_t)(g * LH_ + j) * LH_;
  float s = bih1[g * LH_ + j] + bhh1[g * LH_ + j];
  #pragma unroll 2
  for (int k = 0; k < LH_; k += 2) {
    float2 w2 = *(const float2*)(wr + k);
    s += w2.x * hs[k] + w2.y * hs[k + 1];
  }
  P[(size_t)t * G4_ + o] = s;
}

// ---------------- 4 FC heads ----------------------------------------------
__global__ void k_fc(const float* __restrict__ ylast,
                     const float* __restrict__ Wa, const float* __restrict__ ba,
                     const float* __restrict__ Wb, const float* __restrict__ bb,
                     const float* __restrict__ Wc, const float* __restrict__ bc,
                     const float* __restrict__ Wd, const float* __restrict__ bd,
                     float* __restrict__ out) {
  int wg = blockIdx.x * 4 + (threadIdx.x >> 6);
  int lane = threadIdx.x & 63;
  if (wg >= 4 * OUT_) return;
  int head = wg / OUT_, o = wg - head * OUT_;
  const float* W = head == 0 ? Wa : head == 1 ? Wb : head == 2 ? Wc : Wd;
  const float* b = head == 0 ? ba : head == 1 ? bb : head == 2 ? bc : bd;
  float s = 0.f;
  #pragma unroll
  for (int r = 0; r < 4; ++r) {
    int idx = r * 64 + lane;
    if (idx < LH_) s += ylast[idx] * W[(size_t)o * LH_ + idx];
  }
  #pragma unroll
  for (int off = 32; off > 0; off >>= 1) s += __shfl_xor(s, off, 64);
  if (lane == 0) out[wg] = s + b[o];
}

// ---------------- launch ---------------------------------------------------
extern "C" void kernel_launch(void* const* d_in, const int* in_sizes, int n_in,
                              void* d_out, int out_size, void* d_ws, size_t ws_size,
                              hipStream_t stream) {
  const float* nodes = (const float*)d_in[0];
  const int*   ei    = (const int*)d_in[1];
  const float* W1    = (const float*)d_in[3];
  const float* as1   = (const float*)d_in[4];
  const float* ad1   = (const float*)d_in[5];
  const float* b1    = (const float*)d_in[6];
  const float* W2    = (const float*)d_in[7];
  const float* as2   = (const float*)d_in[8];
  const float* ad2   = (const float*)d_in[9];
  const float* b2    = (const float*)d_in[10];
  const float* Wih0  = (const float*)d_in[11];
  const float* Whh0  = (const float*)d_in[12];
  const float* bih0  = (const float*)d_in[13];
  const float* bhh0  = (const float*)d_in[14];
  const float* Wih1  = (const float*)d_in[15];
  const float* Whh1  = (const float*)d_in[16];
  const float* bih1  = (const float*)d_in[17];
  const float* bhh1  = (const float*)d_in[18];
  const float* h0    = (const float*)d_in[19];
  const float* c0    = (const float*)d_in[20];
  const float* fW1   = (const float*)d_in[21];
  const float* fb1   = (const float*)d_in[22];
  const float* fW2   = (const float*)d_in[23];
  const float* fb2   = (const float*)d_in[24];
  const float* fW3   = (const float*)d_in[25];
  const float* fb3   = (const float*)d_in[26];
  const float* fW4   = (const float*)d_in[27];
  const float* fb4   = (const float*)d_in[28];
  float* out = (float*)d_out;

  // workspace layout (bytes). Gpart overlaps dead Hbuf/HS/HD/X1 region.
  const size_t o_Gpart  = 0;          // 60*96*1024*4 = 23,592,960
  const size_t o_H      = 0;
  const size_t o_HS     = 14008320;
  const size_t o_HD     = 14446080;
  const size_t o_X1     = 14883840;
  const size_t o_X2     = 28892160;
  const size_t o_counts = 42900480;
  const size_t o_offs   = 43338240;
  const size_t o_cursor = 43776512;
  const size_t o_elist  = 44214272;
  const size_t o_G0     = 52969472;   // 384,000
  const size_t o_ylast  = 53353472;   // 1,024
  const size_t o_h0seq  = 53354496;   // 96*256*4 = 98,304
  const size_t o_P      = 53452800;   // 96*1000*4 = 384,000
  const size_t total    = 53836800;
  if (ws_size < total) return;  // leaves d_out poisoned -> visible failure

  char* ws = (char*)d_ws;
  float* Gpart  = (float*)(ws + o_Gpart);
  float* Hbuf   = (float*)(ws + o_H);
  float* HS     = (float*)(ws + o_HS);
  float* HD     = (float*)(ws + o_HD);
  float* X1     = (float*)(ws + o_X1);
  float* X2     = (float*)(ws + o_X2);
  int*   counts = (int*)(ws + o_counts);
  int*   offs   = (int*)(ws + o_offs);
  int*   cursor = (int*)(ws + o_cursor);
  int*   elist  = (int*)(ws + o_elist);
  float* G0     = (float*)(ws + o_G0);
  float* ylast  = (float*)(ws + o_ylast);
  float* h0seq  = (float*)(ws + o_h0seq);
  float* P      = (float*)(ws + o_P);

  (void)hipMemsetAsync(counts, 0, (size_t)T_ * N_ * 4, stream);

  const int rows_grid = (T_ * N_ * H_) / 256;   // 13680
  const int eg = (T_ * E_ + 255) / 256;         // 8550

  // GAT layer 1
  k_feat<<<rows_grid, 256, 0, stream>>>(nodes, W1, as1, ad1, Hbuf, HS, HD, F_);
  k_count<<<eg, 256, 0, stream>>>(ei, counts);
  k_scan<<<T_, 256, 0, stream>>>(counts, offs, cursor);
  k_fill<<<eg, 256, 0, stream>>>(ei, cursor, elist);
  k_aggr<<<rows_grid, 256, 0, stream>>>(Hbuf, HS, HD, offs, elist, b1, X1, 1);
  // GAT layer 2
  k_feat<<<rows_grid, 256, 0, stream>>>(X1, W2, as2, ad2, Hbuf, HS, HD, H_);
  k_aggr<<<rows_grid, 256, 0, stream>>>(Hbuf, HS, HD, offs, elist, b2, X2, 0);
  // LSTM0 input projection (f16 dot2, SPLITK=60)
  k_gemm<<<dim3(32, SPLITK), 128, 0, stream>>>(X2, Wih0, Gpart);
  k_gred<<<(T_ * G4_ + 255) / 256, 256, 0, stream>>>(Gpart, bih0, bhh0, G0);
  // layer-0 recurrence (single WG, register-resident weights)
  k_lstm_seq<<<1, 768, 0, stream>>>(Whh0, G0, h0, c0, h0seq, ylast, 0);
  // batch layer-1 input projection over all t
  k_pgemm<<<T_ * 4, 256, 0, stream>>>(h0seq, Wih1, bih1, bhh1, P);
  // layer-1 recurrence (single WG)
  k_lstm_seq<<<1, 768, 0, stream>>>(Whh1, P, h0 + LH_, c0 + LH_, h0seq, ylast, 1);
  // FC heads
  k_fc<<<OUT_, 256, 0, stream>>>(ylast, fW1, fb1, fW2, fb2, fW3, fb3, fW4, fb4, out);
}

// Round 14
// 1301.081 us; speedup vs baseline: 2.3450x; 1.0433x over previous
//
#include <hip/hip_runtime.h>

#define T_ 96
#define N_ 1140
#define F_ 64
#define H_ 32
#define E_ 22800
#define LH_ 250
#define G4_ 1000
#define OUT_ 2280
#define KIN_ 36480   // N_*H_
#define SPLITK 60
#define KC 32
#define BN 32

typedef _Float16 h2_t __attribute__((ext_vector_type(2)));

__device__ __forceinline__ float leaky02(float x){ return x > 0.f ? x : 0.2f*x; }
__device__ __forceinline__ float fsigm(float x){ return 1.f/(1.f + __expf(-x)); }
__device__ __forceinline__ float ftanh(float x){
  x = fminf(fmaxf(x, -15.f), 15.f);
  float t = __expf(2.f * x);
  return (t - 1.f) / (t + 1.f);
}
__device__ __forceinline__ unsigned packh2(float a, float b) {
  auto p = __builtin_amdgcn_cvt_pkrtz(a, b);   // __fp16 ext_vector(2)
  return __builtin_bit_cast(unsigned, p);
}
__device__ __forceinline__ float fdot2u(unsigned w, unsigned h, float acc) {
  return __builtin_amdgcn_fdot2(__builtin_bit_cast(h2_t, w),
                                __builtin_bit_cast(h2_t, h), acc, false);
}

// ---------------- GAT feature transform: H = x@W, HS = H@a_s, HD = H@a_d ----
__global__ void k_feat(const float* __restrict__ x, const float* __restrict__ W,
                       const float* __restrict__ as_, const float* __restrict__ ad_,
                       float* __restrict__ Hout, float* __restrict__ HS,
                       float* __restrict__ HD, int K) {
  int gid = blockIdx.x * blockDim.x + threadIdx.x;
  int row = gid >> 5; int c = gid & 31;
  if (row >= T_ * N_) return;
  const float* xr = x + (size_t)row * K;
  float acc = 0.f;
  for (int k = 0; k < K; ++k) acc += xr[k] * W[k * H_ + c];
  Hout[(size_t)row * H_ + c] = acc;
  float ps = acc * as_[c], pd = acc * ad_[c];
  #pragma unroll
  for (int off = 16; off > 0; off >>= 1) {
    ps += __shfl_xor(ps, off, 32);
    pd += __shfl_xor(pd, off, 32);
  }
  if (c == 0) { HS[row] = ps; HD[row] = pd; }
}

// ---------------- CSR build ------------------------------------------------
__global__ void k_count(const int* __restrict__ ei, int* __restrict__ counts) {
  int gid = blockIdx.x * blockDim.x + threadIdx.x;
  if (gid >= T_ * E_) return;
  int t = gid / E_; int k = gid - t * E_;
  int dst = ei[(size_t)t * 2 * E_ + E_ + k];
  atomicAdd(&counts[t * N_ + dst], 1);
}

__global__ void k_scan(const int* __restrict__ counts, int* __restrict__ offs,
                       int* __restrict__ cursor) {
  int t = blockIdx.x; int tid = threadIdx.x;
  int base = tid * 5;
  int v[5]; int s = 0;
  #pragma unroll
  for (int r = 0; r < 5; ++r) {
    int i = base + r;
    int c = (i < N_) ? counts[t * N_ + i] : 0;
    v[r] = c; s += c;
  }
  __shared__ int sh[256];
  sh[tid] = s; __syncthreads();
  for (int off = 1; off < 256; off <<= 1) {
    int add = (tid >= off) ? sh[tid - off] : 0;
    __syncthreads();
    sh[tid] += add;
    __syncthreads();
  }
  int run = sh[tid] - s;  // exclusive prefix of this thread's chunk
  #pragma unroll
  for (int r = 0; r < 5; ++r) {
    int i = base + r;
    if (i < N_) { offs[t * (N_ + 1) + i] = run; cursor[t * N_ + i] = run; }
    run += v[r];
  }
  if (tid == 255) offs[t * (N_ + 1) + N_] = sh[255];
}

__global__ void k_fill(const int* __restrict__ ei, int* __restrict__ cursor,
                       int* __restrict__ elist) {
  int gid = blockIdx.x * blockDim.x + threadIdx.x;
  if (gid >= T_ * E_) return;
  int t = gid / E_; int k = gid - t * E_;
  int src = ei[(size_t)t * 2 * E_ + k];
  int dst = ei[(size_t)t * 2 * E_ + E_ + k];
  int pos = atomicAdd(&cursor[t * N_ + dst], 1);
  elist[(size_t)t * E_ + pos] = src;
}

// ---------------- GAT attention aggregate (online softmax per dst) ---------
__global__ void k_aggr(const float* __restrict__ Hf, const float* __restrict__ HS,
                       const float* __restrict__ HD, const int* __restrict__ offs,
                       const int* __restrict__ elist, const float* __restrict__ b,
                       float* __restrict__ Xout, int relu) {
  int gid = blockIdx.x * blockDim.x + threadIdx.x;
  int row = gid >> 5; int c = gid & 31;
  if (row >= T_ * N_) return;
  int t = row / N_; int i = row - t * N_;
  float hd_i = HD[row];
  float m = leaky02(HS[row] + hd_i);   // self-loop
  float s = 1.f;
  float acc = Hf[(size_t)row * H_ + c];
  int e0 = offs[t * (N_ + 1) + i], e1 = offs[t * (N_ + 1) + i + 1];
  const int* el = elist + (size_t)t * E_;
  const float* Ht = Hf + (size_t)t * N_ * H_;
  const float* HSt = HS + t * N_;
  float hsA = 0.f, hvA = 0.f;
  if (e0 < e1) {
    int srcA = el[e0];
    hsA = HSt[srcA];
    hvA = Ht[(size_t)srcA * H_ + c];
  }
  for (int e = e0; e < e1; ++e) {
    float hs = hsA, hv = hvA;
    if (e + 1 < e1) {
      int srcA = el[e + 1];
      hsA = HSt[srcA];
      hvA = Ht[(size_t)srcA * H_ + c];
    }
    float eg = leaky02(hs + hd_i);
    float mn = fmaxf(m, eg);
    float scl = __expf(m - mn);
    float p = __expf(eg - mn);
    s = s * scl + p;
    acc = acc * scl + p * hv;
    m = mn;
  }
  float val = acc / s + b[c];
  if (relu) val = fmaxf(val, 0.f);
  Xout[(size_t)row * H_ + c] = val;
}

// ------- LSTM0 input GEMM (f16 dot2): (96 x 36480) @ (36480 x 1000)^T ------
__global__ void k_gemm(const float* __restrict__ X, const float* __restrict__ Wih,
                       float* __restrict__ Gpart) {
  __shared__ unsigned Xs[T_][KC / 2 + 1];   // f16 pairs along K
  __shared__ unsigned Ws[BN][KC / 2 + 1];
  int j0 = blockIdx.x * BN;
  int sp = blockIdx.y;
  int tid = threadIdx.x;
  int jj = tid & 7;    // 8 j-groups of 4
  int tt = tid >> 3;   // 16 t-groups of 6
  float acc[6][4] = {};
  int kbeg = sp * (KIN_ / SPLITK);
  int kend = kbeg + (KIN_ / SPLITK);
  for (int k0 = kbeg; k0 < kend; k0 += KC) {
    for (int idx = tid; idx < T_ * (KC / 2); idx += 128) {
      int tr = idx >> 4; int kk = idx & 15;
      const float2 v = *(const float2*)(X + (size_t)tr * KIN_ + k0 + 2 * kk);
      Xs[tr][kk] = packh2(v.x, v.y);
    }
    for (int idx = tid; idx < BN * (KC / 2); idx += 128) {
      int jr = idx >> 4; int kk = idx & 15;
      int j = j0 + jr;
      unsigned v = 0;
      if (j < G4_) {
        const float2 w = *(const float2*)(Wih + (size_t)j * KIN_ + k0 + 2 * kk);
        v = packh2(w.x, w.y);
      }
      Ws[jr][kk] = v;
    }
    __syncthreads();
    for (int kk = 0; kk < KC / 2; ++kk) {
      unsigned xv[6], wv[4];
      #pragma unroll
      for (int r = 0; r < 6; ++r) xv[r] = Xs[tt * 6 + r][kk];
      #pragma unroll
      for (int q = 0; q < 4; ++q) wv[q] = Ws[jj * 4 + q][kk];
      #pragma unroll
      for (int r = 0; r < 6; ++r)
        #pragma unroll
        for (int q = 0; q < 4; ++q)
          acc[r][q] = fdot2u(wv[q], xv[r], acc[r][q]);
    }
    __syncthreads();
  }
  #pragma unroll
  for (int r = 0; r < 6; ++r) {
    int t = tt * 6 + r;
    #pragma unroll
    for (int q = 0; q < 4; ++q) {
      int j = j0 + jj * 4 + q;
      if (j < G4_) Gpart[((size_t)sp * T_ + t) * 1024 + j] = acc[r][q];
    }
  }
}

// G0 reduced with gate-interleaved layout: G0[t*1000 + j*4 + g]
__global__ void k_gred(const float* __restrict__ Gpart, const float* __restrict__ bih,
                       const float* __restrict__ bhh, float* __restrict__ G0) {
  int idx = blockIdx.x * blockDim.x + threadIdx.x;
  if (idx >= T_ * G4_) return;
  int t = idx / G4_; int jg = idx - t * G4_;
  int j = jg >> 2, g = jg & 3;
  int c = g * LH_ + j;                      // gate-major column in Gpart
  float s = bih[c] + bhh[c];
  for (int sp = 0; sp < SPLITK; ++sp) s += Gpart[((size_t)sp * T_ + t) * 1024 + c];
  G0[idx] = s;
}

// ---------------- single-WG LSTM layer recurrence (2-way K-split) ----------
// ONE workgroup, 512 threads (8 waves). amdgpu_waves_per_eu(2,2) PINS the
// allocator to 2 waves/SIMD -> full 256-VGPR budget. (R11/R13 lesson:
// __launch_bounds__ only sets the minimum; the allocator's occupancy
// heuristic targeted 4-6 waves/EU and spilled ALL weight arrays to scratch
// -- VGPR_Count 128/84 + WRITE_SIZE ~430KB were the tell.)
// Thread pair (2u,2u+1) owns unit u, one K-half each (64 f16-pairs).
// Gates i,f,g in VGPRs (192 u32, statically indexed, fully unrolled);
// o-gate in LDS as uint2 (128 KiB). sched_barrier(0) every 2 iterations
// stops the scheduler from hoisting LDS reads past the register cap.
// h as _Float16[256] LDS double buffer; 1 barrier/step; zero atomics.
__global__ void __attribute__((amdgpu_flat_work_group_size(512, 512),
                               amdgpu_waves_per_eu(2, 2))) k_lstm_seq(
    const float* __restrict__ Wrec,   // [4*250][250] rows g*250+u, fp32
    const float* __restrict__ GP,     // [96][1000] gate-interleaved u*4+g
    const float* __restrict__ hinit,  // [250]
    const float* __restrict__ cinit,  // [250]
    float* __restrict__ hseq_out,     // role0: [96][256]
    float* __restrict__ ylast,        // role1: [250]
    int role) {
  __shared__ __align__(16) _Float16 ldsH[2][256];
  __shared__ uint2 ldsWO[32 * 512];   // 128 KiB: o-gate pairs-of-pairs
  int tid = threadIdx.x;
  int u = tid >> 1, half = tid & 1;
  bool act = (u < LH_);

  // ---- weight preload (fully unrolled; static register indices) ----
  unsigned wI[64], wF[64], wG[64];
  {
    int uc = act ? u : 0;
    const float* rI = Wrec + (size_t)(0 * LH_ + uc) * LH_;
    const float* rF = Wrec + (size_t)(1 * LH_ + uc) * LH_;
    const float* rG = Wrec + (size_t)(2 * LH_ + uc) * LH_;
    const float* rO = Wrec + (size_t)(3 * LH_ + uc) * LH_;
    #pragma unroll
    for (int q = 0; q < 32; ++q) {
      int m0 = half * 64 + 2 * q, m1 = m0 + 1;
      bool ok0 = act && (m0 < 125), ok1 = act && (m1 < 125);
      float2 vI0 = ok0 ? *(const float2*)(rI + 2 * m0) : make_float2(0.f, 0.f);
      float2 vI1 = ok1 ? *(const float2*)(rI + 2 * m1) : make_float2(0.f, 0.f);
      float2 vF0 = ok0 ? *(const float2*)(rF + 2 * m0) : make_float2(0.f, 0.f);
      float2 vF1 = ok1 ? *(const float2*)(rF + 2 * m1) : make_float2(0.f, 0.f);
      float2 vG0 = ok0 ? *(const float2*)(rG + 2 * m0) : make_float2(0.f, 0.f);
      float2 vG1 = ok1 ? *(const float2*)(rG + 2 * m1) : make_float2(0.f, 0.f);
      float2 vO0 = ok0 ? *(const float2*)(rO + 2 * m0) : make_float2(0.f, 0.f);
      float2 vO1 = ok1 ? *(const float2*)(rO + 2 * m1) : make_float2(0.f, 0.f);
      wI[2 * q]     = packh2(vI0.x, vI0.y);
      wI[2 * q + 1] = packh2(vI1.x, vI1.y);
      wF[2 * q]     = packh2(vF0.x, vF0.y);
      wF[2 * q + 1] = packh2(vF1.x, vF1.y);
      wG[2 * q]     = packh2(vG0.x, vG0.y);
      wG[2 * q + 1] = packh2(vG1.x, vG1.y);
      ldsWO[q * 512 + tid] = make_uint2(packh2(vO0.x, vO0.y), packh2(vO1.x, vO1.y));
      if ((q & 3) == 3) __builtin_amdgcn_sched_barrier(0);
    }
  }
  // ---- init h buffers (tail [250..255] stays zero; weights there are 0) ----
  if (tid < 256) {
    ldsH[0][tid] = (tid < LH_) ? (_Float16)hinit[tid] : (_Float16)0.f;
    ldsH[1][tid] = (_Float16)0.f;
  }
  float c = act ? cinit[u] : 0.f;
  __syncthreads();

  for (int p = 0; p < T_; ++p) {
    int rb = p & 1, wb = rb ^ 1;
    float4 gp = make_float4(0.f, 0.f, 0.f, 0.f);
    if (act) gp = *(const float4*)(GP + (size_t)p * G4_ + 4 * u);
    float sI = 0.f, sF = 0.f, sG = 0.f, sO = 0.f;
    const uint2* h2p = (const uint2*)&ldsH[rb][half * 128];  // 32 pair-of-pairs
    #pragma unroll
    for (int q = 0; q < 32; ++q) {
      uint2 hv = h2p[q];
      uint2 wo = ldsWO[q * 512 + tid];
      sI = fdot2u(wI[2 * q], hv.x, sI);
      sF = fdot2u(wF[2 * q], hv.x, sF);
      sG = fdot2u(wG[2 * q], hv.x, sG);
      sO = fdot2u(wo.x, hv.x, sO);
      sI = fdot2u(wI[2 * q + 1], hv.y, sI);
      sF = fdot2u(wF[2 * q + 1], hv.y, sF);
      sG = fdot2u(wG[2 * q + 1], hv.y, sG);
      sO = fdot2u(wo.y, hv.y, sO);
      if ((q & 1) == 1) __builtin_amdgcn_sched_barrier(0);
    }
    // combine the two K-halves (lanes 2k, 2k+1)
    sI += __shfl_xor(sI, 1); sF += __shfl_xor(sF, 1);
    sG += __shfl_xor(sG, 1); sO += __shfl_xor(sO, 1);
    float preI = sI + gp.x, preF = sF + gp.y;
    float preG = sG + gp.z, preO = sO + gp.w;
    c = fsigm(preF) * c + fsigm(preI) * ftanh(preG);
    float h = act ? (fsigm(preO) * ftanh(c)) : 0.f;
    if (act && half == 0) {
      ldsH[wb][u] = (_Float16)h;
      if (role == 0) hseq_out[p * 256 + u] = h;
      if (role == 1 && p == T_ - 1) ylast[u] = h;
    }
    __syncthreads();
  }
}

// ------- batch layer-1 input projection: P[t] = Wih1 @ h0[t] + b -----------
// grid 96*4 WGs x 256: WG (t, b) computes outputs o = b*256+tid (o = j*4+g).
__global__ void k_pgemm(const float* __restrict__ h0seq, const float* __restrict__ Wih1,
                        const float* __restrict__ bih1, const float* __restrict__ bhh1,
                        float* __restrict__ P) {
  __shared__ float hs[256];
  int t = blockIdx.x >> 2, b = blockIdx.x & 3;
  int tid = threadIdx.x;
  hs[tid] = (tid < LH_) ? h0seq[t * 256 + tid] : 0.f;
  __syncthreads();
  int o = b * 256 + tid;
  if (o >= G4_) return;
  int j = o >> 2, g = o & 3;
  const float* wr = Wih1 + (size_t)(g * LH_ + j) * LH_;
  float s = bih1[g * LH_ + j] + bhh1[g * LH_ + j];
  #pragma unroll 2
  for (int k = 0; k < LH_; k += 2) {
    float2 w2 = *(const float2*)(wr + k);
    s += w2.x * hs[k] + w2.y * hs[k + 1];
  }
  P[(size_t)t * G4_ + o] = s;
}

// ---------------- 4 FC heads ----------------------------------------------
__global__ void k_fc(const float* __restrict__ ylast,
                     const float* __restrict__ Wa, const float* __restrict__ ba,
                     const float* __restrict__ Wb, const float* __restrict__ bb,
                     const float* __restrict__ Wc, const float* __restrict__ bc,
                     const float* __restrict__ Wd, const float* __restrict__ bd,
                     float* __restrict__ out) {
  int wg = blockIdx.x * 4 + (threadIdx.x >> 6);
  int lane = threadIdx.x & 63;
  if (wg >= 4 * OUT_) return;
  int head = wg / OUT_, o = wg - head * OUT_;
  const float* W = head == 0 ? Wa : head == 1 ? Wb : head == 2 ? Wc : Wd;
  const float* b = head == 0 ? ba : head == 1 ? bb : head == 2 ? bc : bd;
  float s = 0.f;
  #pragma unroll
  for (int r = 0; r < 4; ++r) {
    int idx = r * 64 + lane;
    if (idx < LH_) s += ylast[idx] * W[(size_t)o * LH_ + idx];
  }
  #pragma unroll
  for (int off = 32; off > 0; off >>= 1) s += __shfl_xor(s, off, 64);
  if (lane == 0) out[wg] = s + b[o];
}

// ---------------- launch ---------------------------------------------------
extern "C" void kernel_launch(void* const* d_in, const int* in_sizes, int n_in,
                              void* d_out, int out_size, void* d_ws, size_t ws_size,
                              hipStream_t stream) {
  const float* nodes = (const float*)d_in[0];
  const int*   ei    = (const int*)d_in[1];
  const float* W1    = (const float*)d_in[3];
  const float* as1   = (const float*)d_in[4];
  const float* ad1   = (const float*)d_in[5];
  const float* b1    = (const float*)d_in[6];
  const float* W2    = (const float*)d_in[7];
  const float* as2   = (const float*)d_in[8];
  const float* ad2   = (const float*)d_in[9];
  const float* b2    = (const float*)d_in[10];
  const float* Wih0  = (const float*)d_in[11];
  const float* Whh0  = (const float*)d_in[12];
  const float* bih0  = (const float*)d_in[13];
  const float* bhh0  = (const float*)d_in[14];
  const float* Wih1  = (const float*)d_in[15];
  const float* Whh1  = (const float*)d_in[16];
  const float* bih1  = (const float*)d_in[17];
  const float* bhh1  = (const float*)d_in[18];
  const float* h0    = (const float*)d_in[19];
  const float* c0    = (const float*)d_in[20];
  const float* fW1   = (const float*)d_in[21];
  const float* fb1   = (const float*)d_in[22];
  const float* fW2   = (const float*)d_in[23];
  const float* fb2   = (const float*)d_in[24];
  const float* fW3   = (const float*)d_in[25];
  const float* fb3   = (const float*)d_in[26];
  const float* fW4   = (const float*)d_in[27];
  const float* fb4   = (const float*)d_in[28];
  float* out = (float*)d_out;

  // workspace layout (bytes). Gpart overlaps dead Hbuf/HS/HD/X1 region.
  const size_t o_Gpart  = 0;          // 60*96*1024*4 = 23,592,960
  const size_t o_H      = 0;
  const size_t o_HS     = 14008320;
  const size_t o_HD     = 14446080;
  const size_t o_X1     = 14883840;
  const size_t o_X2     = 28892160;
  const size_t o_counts = 42900480;
  const size_t o_offs   = 43338240;
  const size_t o_cursor = 43776512;
  const size_t o_elist  = 44214272;
  const size_t o_G0     = 52969472;   // 384,000
  const size_t o_ylast  = 53353472;   // 1,024
  const size_t o_h0seq  = 53354496;   // 96*256*4 = 98,304
  const size_t o_P      = 53452800;   // 96*1000*4 = 384,000
  const size_t total    = 53836800;
  if (ws_size < total) return;  // leaves d_out poisoned -> visible failure

  char* ws = (char*)d_ws;
  float* Gpart  = (float*)(ws + o_Gpart);
  float* Hbuf   = (float*)(ws + o_H);
  float* HS     = (float*)(ws + o_HS);
  float* HD     = (float*)(ws + o_HD);
  float* X1     = (float*)(ws + o_X1);
  float* X2     = (float*)(ws + o_X2);
  int*   counts = (int*)(ws + o_counts);
  int*   offs   = (int*)(ws + o_offs);
  int*   cursor = (int*)(ws + o_cursor);
  int*   elist  = (int*)(ws + o_elist);
  float* G0     = (float*)(ws + o_G0);
  float* ylast  = (float*)(ws + o_ylast);
  float* h0seq  = (float*)(ws + o_h0seq);
  float* P      = (float*)(ws + o_P);

  (void)hipMemsetAsync(counts, 0, (size_t)T_ * N_ * 4, stream);

  const int rows_grid = (T_ * N_ * H_) / 256;   // 13680
  const int eg = (T_ * E_ + 255) / 256;         // 8550

  // GAT layer 1
  k_feat<<<rows_grid, 256, 0, stream>>>(nodes, W1, as1, ad1, Hbuf, HS, HD, F_);
  k_count<<<eg, 256, 0, stream>>>(ei, counts);
  k_scan<<<T_, 256, 0, stream>>>(counts, offs, cursor);
  k_fill<<<eg, 256, 0, stream>>>(ei, cursor, elist);
  k_aggr<<<rows_grid, 256, 0, stream>>>(Hbuf, HS, HD, offs, elist, b1, X1, 1);
  // GAT layer 2
  k_feat<<<rows_grid, 256, 0, stream>>>(X1, W2, as2, ad2, Hbuf, HS, HD, H_);
  k_aggr<<<rows_grid, 256, 0, stream>>>(Hbuf, HS, HD, offs, elist, b2, X2, 0);
  // LSTM0 input projection (f16 dot2, SPLITK=60)
  k_gemm<<<dim3(32, SPLITK), 128, 0, stream>>>(X2, Wih0, Gpart);
  k_gred<<<(T_ * G4_ + 255) / 256, 256, 0, stream>>>(Gpart, bih0, bhh0, G0);
  // layer-0 recurrence (single WG, register-resident weights)
  k_lstm_seq<<<1, 512, 0, stream>>>(Whh0, G0, h0, c0, h0seq, ylast, 0);
  // batch layer-1 input projection over all t
  k_pgemm<<<T_ * 4, 256, 0, stream>>>(h0seq, Wih1, bih1, bhh1, P);
  // layer-1 recurrence (single WG)
  k_lstm_seq<<<1, 512, 0, stream>>>(Whh1, P, h0 + LH_, c0 + LH_, h0seq, ylast, 1);
  // FC heads
  k_fc<<<OUT_, 256, 0, stream>>>(ylast, fW1, fb1, fW2, fb2, fW3, fb3, fW4, fb4, out);
}